// Round 12
// baseline (347.191 us; speedup 1.0000x reference)
//
#include <hip/hip_runtime.h>
#include <stdint.h>

// Sparse strided conv: scatter (features@W1 -> grid) + gather (grid@W2 -> out).
// R12: scatter atomics ELIMINATED via inverse rulebook. Stride-2 parity makes
//      voxel->row injective per kv, so inv[row][27] (one contributor per cell)
//      inverts the map. Scatter becomes output-major (mirror of gather_v):
//      wave owns 16 rows, loops 27 kv, masked A-loads of feat[inv[g][kv]],
//      f32 MFMA accum, ONE plain 128B store per grid row. No atomics, no grid
//      zero-init. Duplicate-coord voxels (~600 pairs, random coords) collide
//      in inv: k_inv CAS-claims, losers go to a spill list applied atomically
//      AFTER the store pass. (R11 proved scatter was atomic-RMW-bound: 13M
//      dword atomics = ~100us regardless of occupancy/structure.)

#define N_VOX 120000
#define IC 32
#define OC 64
#define NKV 27
#define DZ 21
#define HY 200
#define WX 176
#define TBL_BITS 20
#define TBL_SIZE (1 << TBL_BITS)
#define TBL_MASK (TBL_SIZE - 1)
#define MAXROWS 480000
#define SPILLCAP 65536

// ws layout (bytes); R1 passing proved ws_size >= 144,228,864
#define OFF_KEYS 0                 // 4,194,304
#define OFF_VALS 4194304           // 4,194,304
#define OFF_CNT 8388608            // 256 (cnt[0]=rows, cnt[1]=spill)
#define OFF_ROWS 8388864           // 12,960,000
#define OFF_FEATB 21348864         // 7,680,000
#define OFF_W2T 29028864           // 110,592
#define OFF_W1T 29139456           // 110,592
#define OFF_SPILL 29250048         // 524,288
#define OFF_INV 29774336           // 51,840,000
#define OFF_GRID 81614336          // 61,440,000
#define WS_NEEDED (OFF_GRID + (size_t)MAXROWS * OC * 2)  // 143,054,336

typedef __attribute__((ext_vector_type(8))) short short8;
typedef __attribute__((ext_vector_type(4))) float f32x4;

__device__ __forceinline__ uint32_t hash_lin(int lin) {
    return ((uint32_t)lin * 2654435761u) >> (32 - TBL_BITS);
}

__device__ __forceinline__ void atomPkBf16(uint16_t* p, uint32_t v) {
    asm volatile("global_atomic_pk_add_bf16 %0, %1, off" :: "v"(p), "v"(v) : "memory");
}

// RTNE f32 -> bf16 pair pack
__device__ __forceinline__ uint32_t pk_bf16(float a, float b) {
    uint32_t x = __float_as_uint(a), y = __float_as_uint(b);
    x = (x + 0x7fffu + ((x >> 16) & 1u)) >> 16;
    y = (y + 0x7fffu + ((y >> 16) & 1u)) >> 16;
    return x | (y << 16);
}
__device__ __forceinline__ uint16_t f2bf(float a) {
    uint32_t x = __float_as_uint(a);
    return (uint16_t)((x + 0x7fffu + ((x >> 16) & 1u)) >> 16);
}
__device__ __forceinline__ float bf2f(uint16_t u) {
    return __uint_as_float(((uint32_t)u) << 16);
}

__global__ void k_init(int* keys, int* counter,
                       const float2* __restrict__ feat2, uint32_t* featb,
                       const float* __restrict__ W1, uint16_t* w1t,
                       const float* __restrict__ W2, uint16_t* w2t) {
    int i = blockIdx.x * blockDim.x + threadIdx.x;
    int stride = gridDim.x * blockDim.x;
    for (int j = i; j < TBL_SIZE; j += stride) keys[j] = -1;
    for (int j = i; j < N_VOX * IC / 2; j += stride) {
        float2 f = feat2[j];
        featb[j] = pk_bf16(f.x, f.y);
    }
    // W1 [kv][c][o] f32 -> w1t [kv][o][c] bf16
    for (int j = i; j < NKV * IC * OC; j += stride) {
        int kv = j >> 11, c = (j >> 6) & 31, o = j & 63;
        w1t[(kv << 11) + (o << 5) + c] = f2bf(W1[j]);
    }
    // W2 [kv][o][c] f32 -> w2t [kv][c][o] bf16
    for (int j = i; j < NKV * OC * IC; j += stride) {
        int kv = j >> 11, o = (j >> 5) & 63, c = j & 31;
        w2t[(kv << 11) + (c << 6) + o] = f2bf(W2[j]);
    }
    if (i == 0) { counter[0] = 0; counter[1] = 0; }
}

__global__ void k_build(const int* __restrict__ coors, int* keys, int* rows) {
    int v = blockIdx.x * blockDim.x + threadIdx.x;
    if (v >= N_VOX) return;
    int b = coors[v * 4 + 0];
    int z = coors[v * 4 + 1];
    int y = coors[v * 4 + 2];
    int x = coors[v * 4 + 3];
#pragma unroll
    for (int kv = 0; kv < NKV; ++kv) {
        int oz = kv / 9, oy = (kv / 3) % 3, ox = kv % 3;
        int az = z + 1 - oz, ay = y + 1 - oy, ax = x + 1 - ox;
        int slot = -1;
        bool valid = (az >= 0) && !(az & 1) && ((az >> 1) < DZ) &&
                     (ay >= 0) && !(ay & 1) && ((ay >> 1) < HY) &&
                     (ax >= 0) && !(ax & 1) && ((ax >> 1) < WX);
        if (valid) {
            int lin = ((b * DZ + (az >> 1)) * HY + (ay >> 1)) * WX + (ax >> 1);
            uint32_t h = hash_lin(lin);
            for (;;) {
                int k = atomicCAS(&keys[h], -1, lin);
                if (k == -1 || k == lin) { slot = (int)h; break; }
                h = (h + 1) & TBL_MASK;
            }
        }
        rows[kv * N_VOX + v] = slot;
    }
}

// Block-aggregated compaction (1 atomic/block) + fused init of the block's
// claimed rows' inv entries to -1 (27 ints per row, contiguous).
__global__ __launch_bounds__(256) void k_assign(const int* __restrict__ keys,
                                                int* __restrict__ vals,
                                                int* counter,
                                                int* __restrict__ inv) {
    const int t = threadIdx.x;
    const int s0 = blockIdx.x * 2048 + t * 8;
    const int4 a = ((const int4*)(keys + s0))[0];
    const int4 b = ((const int4*)(keys + s0))[1];
    int k[8] = {a.x, a.y, a.z, a.w, b.x, b.y, b.z, b.w};
    int c = 0;
#pragma unroll
    for (int i = 0; i < 8; ++i) c += (k[i] != -1);

    __shared__ int sc[256];
    __shared__ int base;
    sc[t] = c;
    __syncthreads();
#pragma unroll
    for (int d = 1; d < 256; d <<= 1) {
        int y = (t >= d) ? sc[t - d] : 0;
        __syncthreads();
        sc[t] += y;
        __syncthreads();
    }
    if (t == 255) base = atomicAdd(&counter[0], sc[255]);
    __syncthreads();
    const int total = sc[255];
    int r = base + sc[t] - c;  // exclusive prefix
#pragma unroll
    for (int i = 0; i < 8; ++i) {
        if (k[i] != -1) { vals[s0 + i] = (r < MAXROWS) ? r : -1; ++r; }
    }
    // init inv for claimed rows [base, base+total): 27 ints each = -1
    int zs = min(base, MAXROWS), ze = min(base + total, MAXROWS);
    for (int i = zs * NKV + t; i < ze * NKV; i += 256) inv[i] = -1;
}

__global__ void k_rows_fix(int* rows, const int* __restrict__ vals) {
    int i = blockIdx.x * blockDim.x + threadIdx.x;
    if (i >= NKV * N_VOX) return;
    int s = rows[i];
    rows[i] = (s >= 0) ? vals[s] : -1;
}

// Invert the rulebook: inv[row*27+kv] = v (unique per (row,kv) by stride-2
// parity injectivity, EXCEPT duplicate-coordinate voxels -> CAS, losers spill).
__global__ void k_inv(const int* __restrict__ rows, int* inv,
                      int* spill, int* counter) {
    int i = blockIdx.x * blockDim.x + threadIdx.x;
    if (i >= NKV * N_VOX) return;
    int row = rows[i];
    if (row < 0) return;
    int kv = i / N_VOX;
    int v = i - kv * N_VOX;
    int old = atomicCAS(&inv[row * NKV + kv], -1, v);
    if (old != -1) {  // duplicate coords: second contributor to (row,kv)
        int s = atomicAdd(&counter[1], 1);
        if (s < SPILLCAP) {
            spill[2 * s] = row;
            spill[2 * s + 1] = (kv << 20) | v;
        }
    }
}

// Scatter, OUTPUT-major MFMA (mirror of gather_v). Wave owns 16 grid rows;
// loops 27 kv: masked per-lane A-loads of feat[inv[g][kv]] (zero if none),
// B = W1^T frags, f32 accum; epilogue: ONE plain 32B-sector store burst per
// row (shfl_xor(1) + even lanes, uint32 stores). No atomics, no zero-init.
// D: col(li)=channel nt*16+li, row(lg*4+rg)=grid row.
__global__ __launch_bounds__(256) void k_scatter_o(
    const uint16_t* __restrict__ featb, const uint16_t* __restrict__ w1t,
    const int* __restrict__ inv, const int* __restrict__ counter,
    uint16_t* __restrict__ gridb) {
    const int wid = threadIdx.x >> 6;
    const int lane = threadIdx.x & 63;
    const int nrows = min(counter[0], MAXROWS);
    const int g0 = (blockIdx.x * 4 + wid) * 16;
    if (g0 >= nrows) return;
    const int lg = lane >> 4;
    const int li = lane & 15;
    const bool rowok = (g0 + li) < nrows;

    f32x4 acc[4] = {{0.f, 0.f, 0.f, 0.f}, {0.f, 0.f, 0.f, 0.f},
                    {0.f, 0.f, 0.f, 0.f}, {0.f, 0.f, 0.f, 0.f}};

    for (int kv = 0; kv < NKV; ++kv) {
        // A-operand: m = grid row g0+li, k = input channel lg*8..+8
        const int v = rowok ? inv[(size_t)(g0 + li) * NKV + kv] : -1;
        short8 a = {0, 0, 0, 0, 0, 0, 0, 0};
        if (v >= 0) a = *(const short8*)(featb + (size_t)v * IC + lg * 8);
        const uint16_t* w1k = w1t + (kv << 11);
#pragma unroll
        for (int nt = 0; nt < 4; ++nt) {
            // B-operand: n = out-channel nt*16+li, k = c
            const short8 b = *(const short8*)(w1k + (nt * 16 + li) * IC + lg * 8);
            acc[nt] = __builtin_amdgcn_mfma_f32_16x16x32_bf16(a, b, acc[nt], 0, 0, 0);
        }
    }
#pragma unroll
    for (int nt = 0; nt < 4; ++nt) {
#pragma unroll
        for (int rg = 0; rg < 4; ++rg) {
            const int g = g0 + lg * 4 + rg;
            float other = __shfl_xor(acc[nt][rg], 1, 64);
            if ((li & 1) == 0 && g < nrows) {
                *(uint32_t*)(gridb + (size_t)g * OC + nt * 16 + li) =
                    pk_bf16(acc[nt][rg], other);
            }
        }
    }
}

// Apply spilled (duplicate-coord) contributions atomically AFTER the store
// pass. ~2K entries expected; one wave per entry, lane = out channel.
__global__ void k_spill(const uint16_t* __restrict__ featb,
                        const uint16_t* __restrict__ w1t,
                        const int* __restrict__ spill,
                        const int* __restrict__ counter,
                        uint16_t* gridb) {
    const int nspill = min(counter[1], SPILLCAP);
    const int lane = threadIdx.x & 63;
    const int wstride = gridDim.x * (blockDim.x >> 6);
    for (int s = blockIdx.x * (blockDim.x >> 6) + (threadIdx.x >> 6);
         s < nspill; s += wstride) {
        const int row = spill[2 * s];
        const int kvv = spill[2 * s + 1];
        const int kv = kvv >> 20;
        const int v = kvv & 0xFFFFF;
        const uint16_t* f = featb + (size_t)v * IC;
        const uint16_t* wr = w1t + (kv << 11) + lane * IC;
        float acc = 0.f;
#pragma unroll
        for (int c = 0; c < IC; ++c) acc += bf2f(f[c]) * bf2f(wr[c]);
        float other = __shfl_xor(acc, 1, 64);
        if ((lane & 1) == 0)
            atomPkBf16(gridb + (size_t)row * OC + lane, pk_bf16(acc, other));
    }
}

// Gather, v-major MFMA (R6, unchanged). Wave owns 32 voxels; loops 27 kv;
// masked A-loads of grid rows + W2^T B-frags; f32 accum; one plain store.
__global__ __launch_bounds__(256) void k_gather_v(
    const uint16_t* __restrict__ gridb, const uint16_t* __restrict__ w2t,
    const int* __restrict__ rows, float* __restrict__ out) {
    const int wid = threadIdx.x >> 6;
    const int lane = threadIdx.x & 63;
    const int v0 = (blockIdx.x * 4 + wid) * 32;
    if (v0 >= N_VOX) return;
    const int lg = lane >> 4;
    const int li = lane & 15;

    f32x4 acc[2][2] = {{{0.f, 0.f, 0.f, 0.f}, {0.f, 0.f, 0.f, 0.f}},
                       {{0.f, 0.f, 0.f, 0.f}, {0.f, 0.f, 0.f, 0.f}}};

    for (int kv = 0; kv < NKV; ++kv) {
        const int* rkv = rows + kv * N_VOX;
        const uint16_t* w2k = w2t + ((size_t)kv << 11);
        short8 b[2][2];  // [ntile][khalf]
#pragma unroll
        for (int nt = 0; nt < 2; ++nt)
#pragma unroll
            for (int kh = 0; kh < 2; ++kh)
                b[nt][kh] = *(const short8*)(w2k + (nt * 16 + li) * 64 +
                                             kh * 32 + lg * 8);
#pragma unroll
        for (int mt = 0; mt < 2; ++mt) {
            const int v = v0 + mt * 16 + li;
            const int r = rkv[v];
            short8 a0 = {0, 0, 0, 0, 0, 0, 0, 0};
            short8 a1 = {0, 0, 0, 0, 0, 0, 0, 0};
            if (r >= 0) {
                const uint16_t* gr = gridb + (size_t)r * OC;
                a0 = *(const short8*)(gr + lg * 8);        // k = 0..31
                a1 = *(const short8*)(gr + 32 + lg * 8);   // k = 32..63
            }
            acc[mt][0] = __builtin_amdgcn_mfma_f32_16x16x32_bf16(a0, b[0][0], acc[mt][0], 0, 0, 0);
            acc[mt][0] = __builtin_amdgcn_mfma_f32_16x16x32_bf16(a1, b[0][1], acc[mt][0], 0, 0, 0);
            acc[mt][1] = __builtin_amdgcn_mfma_f32_16x16x32_bf16(a0, b[1][0], acc[mt][1], 0, 0, 0);
            acc[mt][1] = __builtin_amdgcn_mfma_f32_16x16x32_bf16(a1, b[1][1], acc[mt][1], 0, 0, 0);
        }
    }
#pragma unroll
    for (int mt = 0; mt < 2; ++mt)
#pragma unroll
        for (int nt = 0; nt < 2; ++nt)
#pragma unroll
            for (int rg = 0; rg < 4; ++rg) {
                const int v = v0 + mt * 16 + lg * 4 + rg;
                out[(size_t)v * IC + nt * 16 + li] = acc[mt][nt][rg];
            }
}

extern "C" void kernel_launch(void* const* d_in, const int* in_sizes, int n_in,
                              void* d_out, int out_size, void* d_ws, size_t ws_size,
                              hipStream_t stream) {
    const float* feat = (const float*)d_in[0];
    const int* coors = (const int*)d_in[1];
    const float* W1 = (const float*)d_in[2];
    const float* W2 = (const float*)d_in[3];
    float* out = (float*)d_out;

    if (ws_size < WS_NEEDED) return;  // loud failure: out stays poisoned

    char* ws = (char*)d_ws;
    int* keys = (int*)(ws + OFF_KEYS);
    int* vals = (int*)(ws + OFF_VALS);
    int* counter = (int*)(ws + OFF_CNT);
    int* rows = (int*)(ws + OFF_ROWS);
    uint32_t* featb = (uint32_t*)(ws + OFF_FEATB);
    uint16_t* w2t = (uint16_t*)(ws + OFF_W2T);
    uint16_t* w1t = (uint16_t*)(ws + OFF_W1T);
    int* spill = (int*)(ws + OFF_SPILL);
    int* inv = (int*)(ws + OFF_INV);
    uint16_t* gridb = (uint16_t*)(ws + OFF_GRID);

    k_init<<<dim3(4096), dim3(256), 0, stream>>>(keys, counter,
                                                 (const float2*)feat, featb,
                                                 W1, w1t, W2, w2t);
    k_build<<<dim3((N_VOX + 255) / 256), dim3(256), 0, stream>>>(coors, keys, rows);
    k_assign<<<dim3(TBL_SIZE / 2048), dim3(256), 0, stream>>>(keys, vals, counter,
                                                              inv);
    k_rows_fix<<<dim3((NKV * N_VOX + 255) / 256), dim3(256), 0, stream>>>(rows, vals);
    k_inv<<<dim3((NKV * N_VOX + 255) / 256), dim3(256), 0, stream>>>(rows, inv,
                                                                     spill, counter);
    // output-major scatter: 16 rows/wave, 4 waves/block over MAXROWS
    k_scatter_o<<<dim3(MAXROWS / 64), dim3(256), 0, stream>>>(
        (const uint16_t*)featb, w1t, inv, counter, gridb);
    k_spill<<<dim3(64), dim3(256), 0, stream>>>((const uint16_t*)featb, w1t,
                                                spill, counter, gridb);
    // gather: 32 vox/wave, 4 waves/block
    k_gather_v<<<dim3((N_VOX + 127) / 128), dim3(256), 0, stream>>>(gridb, w2t,
                                                                    rows, out);
}

// Round 13
// 271.020 us; speedup vs baseline: 1.2811x; 1.2811x over previous
//
#include <hip/hip_runtime.h>
#include <stdint.h>

// Sparse strided conv: scatter (features@W1 -> grid) + gather (grid@W2 -> out).
// R13: inverse-rulebook scatter (R12) with the latency chain fixed:
//   - inv TRANSPOSED to inv_t[kv][row]: per-kv reads are one coalesced 64B
//     line per 16-row tile (was 16 scattered lines 108B apart, 27x per wave,
//     each gating a dependent random feat gather -> latency-bound, 180us).
//   - full unroll over kv: 27 independent inv_t loads issue ahead.
//   - ballot skip: ~51% of (tile,kv) cells have zero contributors (avg 1.1
//     contributors/row over 27 kv) -> skip gather + 4 MFMAs.

#define N_VOX 120000
#define IC 32
#define OC 64
#define NKV 27
#define DZ 21
#define HY 200
#define WX 176
#define TBL_BITS 20
#define TBL_SIZE (1 << TBL_BITS)
#define TBL_MASK (TBL_SIZE - 1)
#define MAXROWS 480000
#define SPILLCAP 65536

// ws layout (bytes); R1 passing proved ws_size >= 144,228,864
#define OFF_KEYS 0                 // 4,194,304
#define OFF_VALS 4194304           // 4,194,304
#define OFF_CNT 8388608            // 256 (cnt[0]=rows, cnt[1]=spill)
#define OFF_ROWS 8388864           // 12,960,000
#define OFF_FEATB 21348864         // 7,680,000
#define OFF_W2T 29028864           // 110,592
#define OFF_W1T 29139456           // 110,592
#define OFF_SPILL 29250048         // 524,288
#define OFF_INV 29774336           // 51,840,000 (inv_t[27][MAXROWS])
#define OFF_GRID 81614336          // 61,440,000
#define WS_NEEDED (OFF_GRID + (size_t)MAXROWS * OC * 2)  // 143,054,336

typedef __attribute__((ext_vector_type(8))) short short8;
typedef __attribute__((ext_vector_type(4))) float f32x4;

__device__ __forceinline__ uint32_t hash_lin(int lin) {
    return ((uint32_t)lin * 2654435761u) >> (32 - TBL_BITS);
}

__device__ __forceinline__ void atomPkBf16(uint16_t* p, uint32_t v) {
    asm volatile("global_atomic_pk_add_bf16 %0, %1, off" :: "v"(p), "v"(v) : "memory");
}

// RTNE f32 -> bf16 pair pack
__device__ __forceinline__ uint32_t pk_bf16(float a, float b) {
    uint32_t x = __float_as_uint(a), y = __float_as_uint(b);
    x = (x + 0x7fffu + ((x >> 16) & 1u)) >> 16;
    y = (y + 0x7fffu + ((y >> 16) & 1u)) >> 16;
    return x | (y << 16);
}
__device__ __forceinline__ uint16_t f2bf(float a) {
    uint32_t x = __float_as_uint(a);
    return (uint16_t)((x + 0x7fffu + ((x >> 16) & 1u)) >> 16);
}
__device__ __forceinline__ float bf2f(uint16_t u) {
    return __uint_as_float(((uint32_t)u) << 16);
}

__global__ void k_init(int* keys, int* counter,
                       const float2* __restrict__ feat2, uint32_t* featb,
                       const float* __restrict__ W1, uint16_t* w1t,
                       const float* __restrict__ W2, uint16_t* w2t) {
    int i = blockIdx.x * blockDim.x + threadIdx.x;
    int stride = gridDim.x * blockDim.x;
    for (int j = i; j < TBL_SIZE; j += stride) keys[j] = -1;
    for (int j = i; j < N_VOX * IC / 2; j += stride) {
        float2 f = feat2[j];
        featb[j] = pk_bf16(f.x, f.y);
    }
    // W1 [kv][c][o] f32 -> w1t [kv][o][c] bf16
    for (int j = i; j < NKV * IC * OC; j += stride) {
        int kv = j >> 11, c = (j >> 6) & 31, o = j & 63;
        w1t[(kv << 11) + (o << 5) + c] = f2bf(W1[j]);
    }
    // W2 [kv][o][c] f32 -> w2t [kv][c][o] bf16
    for (int j = i; j < NKV * OC * IC; j += stride) {
        int kv = j >> 11, o = (j >> 5) & 63, c = j & 31;
        w2t[(kv << 11) + (c << 6) + o] = f2bf(W2[j]);
    }
    if (i == 0) { counter[0] = 0; counter[1] = 0; }
}

__global__ void k_build(const int* __restrict__ coors, int* keys, int* rows) {
    int v = blockIdx.x * blockDim.x + threadIdx.x;
    if (v >= N_VOX) return;
    int b = coors[v * 4 + 0];
    int z = coors[v * 4 + 1];
    int y = coors[v * 4 + 2];
    int x = coors[v * 4 + 3];
#pragma unroll
    for (int kv = 0; kv < NKV; ++kv) {
        int oz = kv / 9, oy = (kv / 3) % 3, ox = kv % 3;
        int az = z + 1 - oz, ay = y + 1 - oy, ax = x + 1 - ox;
        int slot = -1;
        bool valid = (az >= 0) && !(az & 1) && ((az >> 1) < DZ) &&
                     (ay >= 0) && !(ay & 1) && ((ay >> 1) < HY) &&
                     (ax >= 0) && !(ax & 1) && ((ax >> 1) < WX);
        if (valid) {
            int lin = ((b * DZ + (az >> 1)) * HY + (ay >> 1)) * WX + (ax >> 1);
            uint32_t h = hash_lin(lin);
            for (;;) {
                int k = atomicCAS(&keys[h], -1, lin);
                if (k == -1 || k == lin) { slot = (int)h; break; }
                h = (h + 1) & TBL_MASK;
            }
        }
        rows[kv * N_VOX + v] = slot;
    }
}

// Block-aggregated compaction (1 atomic/block) + fused init of the block's
// claimed rows' inv_t entries to -1 (27 contiguous runs, one per kv).
__global__ __launch_bounds__(256) void k_assign(const int* __restrict__ keys,
                                                int* __restrict__ vals,
                                                int* counter,
                                                int* __restrict__ invt) {
    const int t = threadIdx.x;
    const int s0 = blockIdx.x * 2048 + t * 8;
    const int4 a = ((const int4*)(keys + s0))[0];
    const int4 b = ((const int4*)(keys + s0))[1];
    int k[8] = {a.x, a.y, a.z, a.w, b.x, b.y, b.z, b.w};
    int c = 0;
#pragma unroll
    for (int i = 0; i < 8; ++i) c += (k[i] != -1);

    __shared__ int sc[256];
    __shared__ int base;
    sc[t] = c;
    __syncthreads();
#pragma unroll
    for (int d = 1; d < 256; d <<= 1) {
        int y = (t >= d) ? sc[t - d] : 0;
        __syncthreads();
        sc[t] += y;
        __syncthreads();
    }
    if (t == 255) base = atomicAdd(&counter[0], sc[255]);
    __syncthreads();
    const int total = sc[255];
    int r = base + sc[t] - c;  // exclusive prefix
#pragma unroll
    for (int i = 0; i < 8; ++i) {
        if (k[i] != -1) { vals[s0 + i] = (r < MAXROWS) ? r : -1; ++r; }
    }
    // init inv_t for claimed rows [base, base+total) across all 27 kv planes
    int zs = min(base, MAXROWS), ze = min(base + total, MAXROWS);
    for (int kv = 0; kv < NKV; ++kv)
        for (int i = zs + t; i < ze; i += 256) invt[kv * MAXROWS + i] = -1;
}

__global__ void k_rows_fix(int* rows, const int* __restrict__ vals) {
    int i = blockIdx.x * blockDim.x + threadIdx.x;
    if (i >= NKV * N_VOX) return;
    int s = rows[i];
    rows[i] = (s >= 0) ? vals[s] : -1;
}

// Invert the rulebook: inv_t[kv][row] = v (unique per (row,kv) by stride-2
// parity injectivity, EXCEPT duplicate-coordinate voxels -> CAS, losers spill).
__global__ void k_inv(const int* __restrict__ rows, int* invt,
                      int* spill, int* counter) {
    int i = blockIdx.x * blockDim.x + threadIdx.x;
    if (i >= NKV * N_VOX) return;
    int row = rows[i];
    if (row < 0) return;
    int kv = i / N_VOX;
    int v = i - kv * N_VOX;
    int old = atomicCAS(&invt[kv * MAXROWS + row], -1, v);
    if (old != -1) {  // duplicate coords: second contributor to (row,kv)
        int s = atomicAdd(&counter[1], 1);
        if (s < SPILLCAP) {
            spill[2 * s] = row;
            spill[2 * s + 1] = (kv << 20) | v;
        }
    }
}

// Scatter, OUTPUT-major MFMA. Wave owns 16 grid rows; full-unrolled 27-kv
// loop: coalesced inv_t load (lane li -> row g0+li, consecutive ints),
// ballot-skip empty kv, masked feat gather, f32 MFMA accum; epilogue: one
// plain 32B-sector store burst per row. No atomics, no zero-init.
// D: col(li)=channel nt*16+li, row(lg*4+rg)=grid row.
__global__ __launch_bounds__(256) void k_scatter_o(
    const uint16_t* __restrict__ featb, const uint16_t* __restrict__ w1t,
    const int* __restrict__ invt, const int* __restrict__ counter,
    uint16_t* __restrict__ gridb) {
    const int wid = threadIdx.x >> 6;
    const int lane = threadIdx.x & 63;
    const int nrows = min(counter[0], MAXROWS);
    const int g0 = (blockIdx.x * 4 + wid) * 16;
    if (g0 >= nrows) return;
    const int lg = lane >> 4;
    const int li = lane & 15;
    const bool rowok = (g0 + li) < nrows;

    f32x4 acc[4] = {{0.f, 0.f, 0.f, 0.f}, {0.f, 0.f, 0.f, 0.f},
                    {0.f, 0.f, 0.f, 0.f}, {0.f, 0.f, 0.f, 0.f}};

#pragma unroll
    for (int kv = 0; kv < NKV; ++kv) {
        // coalesced: lanes of a quarter-wave read 16 consecutive ints
        const int v = rowok ? invt[(size_t)kv * MAXROWS + g0 + li] : -1;
        if (__ballot(v >= 0) == 0) continue;  // no contributor in this tile
        short8 a = {0, 0, 0, 0, 0, 0, 0, 0};
        if (v >= 0) a = *(const short8*)(featb + (size_t)v * IC + lg * 8);
        const uint16_t* w1k = w1t + (kv << 11);
#pragma unroll
        for (int nt = 0; nt < 4; ++nt) {
            const short8 b = *(const short8*)(w1k + (nt * 16 + li) * IC + lg * 8);
            acc[nt] = __builtin_amdgcn_mfma_f32_16x16x32_bf16(a, b, acc[nt], 0, 0, 0);
        }
    }
#pragma unroll
    for (int nt = 0; nt < 4; ++nt) {
#pragma unroll
        for (int rg = 0; rg < 4; ++rg) {
            const int g = g0 + lg * 4 + rg;
            float other = __shfl_xor(acc[nt][rg], 1, 64);
            if ((li & 1) == 0 && g < nrows) {
                *(uint32_t*)(gridb + (size_t)g * OC + nt * 16 + li) =
                    pk_bf16(acc[nt][rg], other);
            }
        }
    }
}

// Apply spilled (duplicate-coord) contributions atomically AFTER the store
// pass. ~600 entries expected; one wave per entry, lane = out channel.
__global__ void k_spill(const uint16_t* __restrict__ featb,
                        const uint16_t* __restrict__ w1t,
                        const int* __restrict__ spill,
                        const int* __restrict__ counter,
                        uint16_t* gridb) {
    const int nspill = min(counter[1], SPILLCAP);
    const int lane = threadIdx.x & 63;
    const int wstride = gridDim.x * (blockDim.x >> 6);
    for (int s = blockIdx.x * (blockDim.x >> 6) + (threadIdx.x >> 6);
         s < nspill; s += wstride) {
        const int row = spill[2 * s];
        const int kvv = spill[2 * s + 1];
        const int kv = kvv >> 20;
        const int v = kvv & 0xFFFFF;
        const uint16_t* f = featb + (size_t)v * IC;
        const uint16_t* wr = w1t + (kv << 11) + lane * IC;
        float acc = 0.f;
#pragma unroll
        for (int c = 0; c < IC; ++c) acc += bf2f(f[c]) * bf2f(wr[c]);
        float other = __shfl_xor(acc, 1, 64);
        if ((lane & 1) == 0)
            atomPkBf16(gridb + (size_t)row * OC + lane, pk_bf16(acc, other));
    }
}

// Gather, v-major MFMA (R6, unchanged). Wave owns 32 voxels; loops 27 kv;
// masked A-loads of grid rows + W2^T B-frags; f32 accum; one plain store.
__global__ __launch_bounds__(256) void k_gather_v(
    const uint16_t* __restrict__ gridb, const uint16_t* __restrict__ w2t,
    const int* __restrict__ rows, float* __restrict__ out) {
    const int wid = threadIdx.x >> 6;
    const int lane = threadIdx.x & 63;
    const int v0 = (blockIdx.x * 4 + wid) * 32;
    if (v0 >= N_VOX) return;
    const int lg = lane >> 4;
    const int li = lane & 15;

    f32x4 acc[2][2] = {{{0.f, 0.f, 0.f, 0.f}, {0.f, 0.f, 0.f, 0.f}},
                       {{0.f, 0.f, 0.f, 0.f}, {0.f, 0.f, 0.f, 0.f}}};

    for (int kv = 0; kv < NKV; ++kv) {
        const int* rkv = rows + kv * N_VOX;
        const uint16_t* w2k = w2t + ((size_t)kv << 11);
        short8 b[2][2];  // [ntile][khalf]
#pragma unroll
        for (int nt = 0; nt < 2; ++nt)
#pragma unroll
            for (int kh = 0; kh < 2; ++kh)
                b[nt][kh] = *(const short8*)(w2k + (nt * 16 + li) * 64 +
                                             kh * 32 + lg * 8);
#pragma unroll
        for (int mt = 0; mt < 2; ++mt) {
            const int v = v0 + mt * 16 + li;
            const int r = rkv[v];
            short8 a0 = {0, 0, 0, 0, 0, 0, 0, 0};
            short8 a1 = {0, 0, 0, 0, 0, 0, 0, 0};
            if (r >= 0) {
                const uint16_t* gr = gridb + (size_t)r * OC;
                a0 = *(const short8*)(gr + lg * 8);        // k = 0..31
                a1 = *(const short8*)(gr + 32 + lg * 8);   // k = 32..63
            }
            acc[mt][0] = __builtin_amdgcn_mfma_f32_16x16x32_bf16(a0, b[0][0], acc[mt][0], 0, 0, 0);
            acc[mt][0] = __builtin_amdgcn_mfma_f32_16x16x32_bf16(a1, b[0][1], acc[mt][0], 0, 0, 0);
            acc[mt][1] = __builtin_amdgcn_mfma_f32_16x16x32_bf16(a0, b[1][0], acc[mt][1], 0, 0, 0);
            acc[mt][1] = __builtin_amdgcn_mfma_f32_16x16x32_bf16(a1, b[1][1], acc[mt][1], 0, 0, 0);
        }
    }
#pragma unroll
    for (int mt = 0; mt < 2; ++mt)
#pragma unroll
        for (int nt = 0; nt < 2; ++nt)
#pragma unroll
            for (int rg = 0; rg < 4; ++rg) {
                const int v = v0 + mt * 16 + lg * 4 + rg;
                out[(size_t)v * IC + nt * 16 + li] = acc[mt][nt][rg];
            }
}

extern "C" void kernel_launch(void* const* d_in, const int* in_sizes, int n_in,
                              void* d_out, int out_size, void* d_ws, size_t ws_size,
                              hipStream_t stream) {
    const float* feat = (const float*)d_in[0];
    const int* coors = (const int*)d_in[1];
    const float* W1 = (const float*)d_in[2];
    const float* W2 = (const float*)d_in[3];
    float* out = (float*)d_out;

    if (ws_size < WS_NEEDED) return;  // loud failure: out stays poisoned

    char* ws = (char*)d_ws;
    int* keys = (int*)(ws + OFF_KEYS);
    int* vals = (int*)(ws + OFF_VALS);
    int* counter = (int*)(ws + OFF_CNT);
    int* rows = (int*)(ws + OFF_ROWS);
    uint32_t* featb = (uint32_t*)(ws + OFF_FEATB);
    uint16_t* w2t = (uint16_t*)(ws + OFF_W2T);
    uint16_t* w1t = (uint16_t*)(ws + OFF_W1T);
    int* spill = (int*)(ws + OFF_SPILL);
    int* invt = (int*)(ws + OFF_INV);
    uint16_t* gridb = (uint16_t*)(ws + OFF_GRID);

    k_init<<<dim3(4096), dim3(256), 0, stream>>>(keys, counter,
                                                 (const float2*)feat, featb,
                                                 W1, w1t, W2, w2t);
    k_build<<<dim3((N_VOX + 255) / 256), dim3(256), 0, stream>>>(coors, keys, rows);
    k_assign<<<dim3(TBL_SIZE / 2048), dim3(256), 0, stream>>>(keys, vals, counter,
                                                              invt);
    k_rows_fix<<<dim3((NKV * N_VOX + 255) / 256), dim3(256), 0, stream>>>(rows, vals);
    k_inv<<<dim3((NKV * N_VOX + 255) / 256), dim3(256), 0, stream>>>(rows, invt,
                                                                     spill, counter);
    // output-major scatter: 16 rows/wave, 4 waves/block over MAXROWS
    k_scatter_o<<<dim3(MAXROWS / 64), dim3(256), 0, stream>>>(
        (const uint16_t*)featb, w1t, invt, counter, gridb);
    k_spill<<<dim3(64), dim3(256), 0, stream>>>((const uint16_t*)featb, w1t,
                                                spill, counter, gridb);
    // gather: 32 vox/wave, 4 waves/block
    k_gather_v<<<dim3((N_VOX + 127) / 128), dim3(256), 0, stream>>>(gridb, w2t,
                                                                    rows, out);
}